// Round 16
// baseline (2554.064 us; speedup 1.0000x reference)
//
#include <hip/hip_runtime.h>
#include <cstdint>

#define NB 128
#define NT 512
#define NL 512
#define NH 512
#define NU 512

// 2*log2(e): tanh(x) = 1 - 2/(exp2(K2E*x)+1); exp2 hoisted into the GEMM epilogue.
static constexpr float K2E = 2.8853900817779268f;

typedef _Float16 h16;
typedef h16 half8 __attribute__((ext_vector_type(8)));
typedef h16 half4 __attribute__((ext_vector_type(4)));
typedef float f32x4 __attribute__((ext_vector_type(4)));

// ---------------------------------------------------------------- K0: sum(V)+bV
__global__ __launch_bounds__(256) void k_sumv(const float* __restrict__ V,
                                              const float* __restrict__ bV,
                                              float* __restrict__ svbv) {
  __shared__ float red[256];
  int tid = threadIdx.x;
  red[tid] = V[tid] + V[tid + 256];
  __syncthreads();
  for (int off = 128; off > 0; off >>= 1) {
    if (tid < off) red[tid] += red[tid + off];
    __syncthreads();
  }
  if (tid == 0) svbv[0] = red[0] + bV[0];
}

// ------------------- K_prep: W [k][n] f32 -> WhT, WlT [n][k] fp16 (split hi/lo)
__global__ __launch_bounds__(256) void k_prep(const float* __restrict__ W,
                                              h16* __restrict__ WhT,
                                              h16* __restrict__ WlT) {
  __shared__ float t[64][65];
  const int tid = threadIdx.x;
  const int k0 = blockIdx.y * 64;
  const int n0 = blockIdx.x * 64;
  const int r = tid >> 4, c4 = (tid & 15) * 4;
#pragma unroll
  for (int p = 0; p < 4; ++p) {
    int k = r + p * 16;
    float4 v = *(const float4*)(W + (size_t)(k0 + k) * NU + n0 + c4);
    t[c4 + 0][k] = v.x;
    t[c4 + 1][k] = v.y;
    t[c4 + 2][k] = v.z;
    t[c4 + 3][k] = v.w;
  }
  __syncthreads();
#pragma unroll
  for (int p = 0; p < 4; ++p) {
    int n = r + p * 16;
    half4 h, l;
    float vv[4] = {t[n][c4 + 0], t[n][c4 + 1], t[n][c4 + 2], t[n][c4 + 3]};
    h.x = (h16)vv[0]; l.x = (h16)(vv[0] - (float)h.x);
    h.y = (h16)vv[1]; l.y = (h16)(vv[1] - (float)h.y);
    h.z = (h16)vv[2]; l.z = (h16)(vv[2] - (float)h.z);
    h.w = (h16)vv[3]; l.w = (h16)(vv[3] - (float)h.w);
    *(half4*)(WhT + (size_t)(n0 + n) * NH + k0 + c4) = h;
    *(half4*)(WlT + (size_t)(n0 + n) * NH + k0 + c4) = l;
  }
}

// -------------- K_prep_a: A [m][k] f32 -> Ah, Al [m][k] fp16 (split hi/lo)
// Pure elementwise, coalesced float4 read / half4 writes. ~45 us per 134 MB.
__global__ __launch_bounds__(256) void k_prep_a(const float* __restrict__ A,
                                                h16* __restrict__ Ah,
                                                h16* __restrict__ Al,
                                                int n4) {
  int idx = blockIdx.x * 256 + threadIdx.x;
  const int stride = gridDim.x * 256;
#pragma unroll 1
  for (int i = idx; i < n4; i += stride) {
    float4 v = ((const float4*)A)[i];
    half4 h, l;
    h.x = (h16)v.x; l.x = (h16)(v.x - (float)h.x);
    h.y = (h16)v.y; l.y = (h16)(v.y - (float)h.y);
    h.z = (h16)v.z; l.z = (h16)(v.z - (float)h.z);
    h.w = (h16)v.w; l.w = (h16)(v.w - (float)h.w);
    ((half4*)Ah)[i] = h;
    ((half4*)Al)[i] = l;
  }
}

// --------------- K1/K2 (direct): out = exp2(K2E*(A@W + bias)) via fp16x3 MFMA
// R16: BOTH operands pre-split fp16 -> no LDS, no barriers, no converts in the
// hot loop. A-frags 16B/lane from Ah/Al [m][k] (rows reused 4x across n-blocks,
// L2-served); B-frags from WhT/WlT [n][k] (L2-resident). 48 MFMA/wave/K-step.
__global__ __launch_bounds__(256) void k_proj_mfma_d(const h16* __restrict__ Ah,
                                                     const h16* __restrict__ Al,
                                                     const h16* __restrict__ WhT,
                                                     const h16* __restrict__ WlT,
                                                     const float* __restrict__ bias,
                                                     float* __restrict__ out) {
  const int tid = threadIdx.x;
  const int m0 = blockIdx.y * 128;
  const int n0 = blockIdx.x * 128;
  const int lane = tid & 63;
  const int wid = tid >> 6;
  const int wm = (wid >> 1) * 64;
  const int wn = (wid & 1) * 64;
  const int fr = lane & 15;
  const int fg = lane >> 4;

  f32x4 acc[4][4];
#pragma unroll
  for (int tm = 0; tm < 4; ++tm)
#pragma unroll
    for (int tn = 0; tn < 4; ++tn) acc[tm][tn] = (f32x4){0.f, 0.f, 0.f, 0.f};

#pragma unroll 1
  for (int kc = 0; kc < 16; ++kc) {
    const int kk = kc * 32 + 8 * fg;
    half8 bh[4], bl[4];
#pragma unroll
    for (int tn = 0; tn < 4; ++tn) {
      size_t boff = (size_t)(n0 + wn + tn * 16 + fr) * NH + kk;
      bh[tn] = *(const half8*)(WhT + boff);
      bl[tn] = *(const half8*)(WlT + boff);
    }
#pragma unroll
    for (int tm = 0; tm < 4; ++tm) {
      size_t aoff = (size_t)(m0 + wm + tm * 16 + fr) * NH + kk;
      half8 ah = *(const half8*)(Ah + aoff);
      half8 al = *(const half8*)(Al + aoff);
#pragma unroll
      for (int tn = 0; tn < 4; ++tn) {
        acc[tm][tn] = __builtin_amdgcn_mfma_f32_16x16x32_f16(ah, bh[tn], acc[tm][tn], 0, 0, 0);
        acc[tm][tn] = __builtin_amdgcn_mfma_f32_16x16x32_f16(ah, bl[tn], acc[tm][tn], 0, 0, 0);
        acc[tm][tn] = __builtin_amdgcn_mfma_f32_16x16x32_f16(al, bh[tn], acc[tm][tn], 0, 0, 0);
      }
    }
  }
#pragma unroll
  for (int tn = 0; tn < 4; ++tn) {
    const int gn = n0 + wn + tn * 16 + fr;
    const float bsv = bias[gn];
#pragma unroll
    for (int tm = 0; tm < 4; ++tm) {
#pragma unroll
      for (int rg = 0; rg < 4; ++rg) {
        int gm = m0 + wm + tm * 16 + 4 * fg + rg;
        out[(size_t)gm * NU + gn] =
            __builtin_amdgcn_exp2f(K2E * (acc[tm][tn][rg] + bsv));
      }
    }
  }
}

// --------------- K1/K2 (fallback, R15-proven): A staged via LDS fp16 split
#define PSTR 40
__global__ __launch_bounds__(256) void k_proj_mfma(const float* __restrict__ A,
                                                   const h16* __restrict__ WhT,
                                                   const h16* __restrict__ WlT,
                                                   const float* __restrict__ bias,
                                                   float* __restrict__ out) {
  __shared__ __align__(16) h16 Ah[128 * PSTR];
  __shared__ __align__(16) h16 Al[128 * PSTR];
  const int tid = threadIdx.x;
  const int m0 = blockIdx.y * 128;
  const int n0 = blockIdx.x * 128;
  const int lane = tid & 63;
  const int wid = tid >> 6;
  const int wm = (wid >> 1) * 64;
  const int wn = (wid & 1) * 64;
  const int fr = lane & 15;
  const int fg = lane >> 4;
  const int ar = tid >> 1, ak = (tid & 1) * 16;

  f32x4 acc[4][4];
#pragma unroll
  for (int tm = 0; tm < 4; ++tm)
#pragma unroll
    for (int tn = 0; tn < 4; ++tn) acc[tm][tn] = (f32x4){0.f, 0.f, 0.f, 0.f};

#pragma unroll 1
  for (int kc = 0; kc < 16; ++kc) {
#pragma unroll
    for (int q = 0; q < 4; ++q) {
      float4 v = *(const float4*)(A + (size_t)(m0 + ar) * NH + kc * 32 + ak + 4 * q);
      half4 h, l;
      h.x = (h16)v.x; l.x = (h16)(v.x - (float)h.x);
      h.y = (h16)v.y; l.y = (h16)(v.y - (float)h.y);
      h.z = (h16)v.z; l.z = (h16)(v.z - (float)h.z);
      h.w = (h16)v.w; l.w = (h16)(v.w - (float)h.w);
      *(half4*)(Ah + ar * PSTR + ak + 4 * q) = h;
      *(half4*)(Al + ar * PSTR + ak + 4 * q) = l;
    }
    __syncthreads();
    half8 bh[4], bl[4];
#pragma unroll
    for (int tn = 0; tn < 4; ++tn) {
      size_t boff = (size_t)(n0 + wn + tn * 16 + fr) * NH + kc * 32 + 8 * fg;
      bh[tn] = *(const half8*)(WhT + boff);
      bl[tn] = *(const half8*)(WlT + boff);
    }
#pragma unroll
    for (int tm = 0; tm < 4; ++tm) {
      half8 ah = *(const half8*)(Ah + (wm + tm * 16 + fr) * PSTR + 8 * fg);
      half8 al = *(const half8*)(Al + (wm + tm * 16 + fr) * PSTR + 8 * fg);
#pragma unroll
      for (int tn = 0; tn < 4; ++tn) {
        acc[tm][tn] = __builtin_amdgcn_mfma_f32_16x16x32_f16(ah, bh[tn], acc[tm][tn], 0, 0, 0);
        acc[tm][tn] = __builtin_amdgcn_mfma_f32_16x16x32_f16(ah, bl[tn], acc[tm][tn], 0, 0, 0);
        acc[tm][tn] = __builtin_amdgcn_mfma_f32_16x16x32_f16(al, bh[tn], acc[tm][tn], 0, 0, 0);
      }
    }
    __syncthreads();
  }
#pragma unroll
  for (int tn = 0; tn < 4; ++tn) {
    const int gn = n0 + wn + tn * 16 + fr;
    const float bsv = bias[gn];
#pragma unroll
    for (int tm = 0; tm < 4; ++tm) {
#pragma unroll
      for (int rg = 0; rg < 4; ++rg) {
        int gm = m0 + wm + tm * 16 + 4 * fg + rg;
        out[(size_t)gm * NU + gn] =
            __builtin_amdgcn_exp2f(K2E * (acc[tm][tn][rg] + bsv));
      }
    }
  }
}

// ---------------------------------------------- K3: S[b,t,l] = base - 2*sum_u V*rc
// R10/R13/R14/R15 version (measured best ~1.52-1.65 ms, VGPR 68, VALUBusy 91%).
__global__ __launch_bounds__(256) void k_score(const float* __restrict__ Ed,
                                               const float* __restrict__ Ee,
                                               const float* __restrict__ Vv,
                                               const float* __restrict__ svbv,
                                               float* __restrict__ out) {
  __shared__ float dpl[64 * 32];
  __shared__ float epl[64 * 32];
  const int tid = threadIdx.x;
  const int b = blockIdx.z;
  const int t0 = blockIdx.y * 64;
  const int l0 = blockIdx.x * 64;
  const int ti = tid & 15;
  const int lj = tid >> 4;
  const int tt = tid & 63;
  const int g0 = (tid >> 6) * 2;
  const float* Edb = Ed + ((size_t)b * NT + t0) * NU;
  const float* Eeb = Ee + ((size_t)b * NL + l0) * NU;
  const int sw = (tt ^ (tt >> 3)) & 7;
  const int pos0 = tt * 32 + 4 * ((g0 + 0) ^ sw);
  const int pos1 = tt * 32 + 4 * ((g0 + 1) ^ sw);
  const size_t srow = (size_t)tt * NU;

  float acc[4][4];
#pragma unroll
  for (int a = 0; a < 4; ++a)
#pragma unroll
    for (int c = 0; c < 4; ++c) acc[a][c] = 0.f;

  {
    float4 d0 = *(const float4*)(Edb + srow + 4 * g0);
    float4 d1 = *(const float4*)(Edb + srow + 4 * g0 + 4);
    float4 e0 = *(const float4*)(Eeb + srow + 4 * g0);
    float4 e1 = *(const float4*)(Eeb + srow + 4 * g0 + 4);
    *(float4*)(dpl + pos0) = d0;
    *(float4*)(dpl + pos1) = d1;
    *(float4*)(epl + pos0) = e0;
    *(float4*)(epl + pos1) = e1;
  }
  __syncthreads();

#pragma unroll 1
  for (int c = 0; c < 16; ++c) {
    float4 pd0, pd1, pe0, pe1;
    if (c < 15) {
      const int uc = (c + 1) * 32;
      pd0 = *(const float4*)(Edb + srow + uc + 4 * g0);
      pd1 = *(const float4*)(Edb + srow + uc + 4 * g0 + 4);
      pe0 = *(const float4*)(Eeb + srow + uc + 4 * g0);
      pe1 = *(const float4*)(Eeb + srow + uc + 4 * g0 + 4);
    }
#pragma unroll 1
    for (int g8 = 0; g8 < 4; ++g8) {
      const float* vb = Vv + c * 32 + g8 * 8;
      const float v0 = vb[0], v1 = vb[1], v2 = vb[2], v3 = vb[3];
      const float v4_ = vb[4], v5 = vb[5], v6 = vb[6], v7 = vb[7];
      float4 bLo[4], bHi[4];
#pragma unroll
      for (int r = 0; r < 4; ++r) {
        int rowb = 4 * lj + r;
        int swb = (rowb ^ (rowb >> 3)) & 7;
        bLo[r] = *(const float4*)(epl + rowb * 32 + 4 * ((2 * g8 + 0) ^ swb));
        bHi[r] = *(const float4*)(epl + rowb * 32 + 4 * ((2 * g8 + 1) ^ swb));
      }
#pragma unroll
      for (int a = 0; a < 4; ++a) {
        int rowa = 4 * ti + a;
        int swa = (rowa ^ (rowa >> 3)) & 7;
        float4 aLo = *(const float4*)(dpl + rowa * 32 + 4 * ((2 * g8 + 0) ^ swa));
        float4 aHi = *(const float4*)(dpl + rowa * 32 + 4 * ((2 * g8 + 1) ^ swa));
#pragma unroll
        for (int cc = 0; cc < 4; ++cc) {
          const float* bp = (const float*)&bLo[cc];
          const float* bh = (const float*)&bHi[cc];
          float d0 = fmaf(aLo.x, bp[0], 1.0f);
          float d1 = fmaf(aLo.y, bp[1], 1.0f);
          float d2 = fmaf(aLo.z, bp[2], 1.0f);
          float d3 = fmaf(aLo.w, bp[3], 1.0f);
          float d4 = fmaf(aHi.x, bh[0], 1.0f);
          float d5 = fmaf(aHi.y, bh[1], 1.0f);
          float d6 = fmaf(aHi.z, bh[2], 1.0f);
          float d7 = fmaf(aHi.w, bh[3], 1.0f);
          float d01 = d0 * d1, d23 = d2 * d3, d45 = d4 * d5, d67 = d6 * d7;
          float n01 = fmaf(v0, d1, v1 * d0);
          float n23 = fmaf(v2, d3, v3 * d2);
          float n45 = fmaf(v4_, d5, v5 * d4);
          float n67 = fmaf(v6, d7, v7 * d6);
          float n03 = fmaf(n01, d23, n23 * d01);
          float d03 = d01 * d23;
          float n47 = fmaf(n45, d67, n67 * d45);
          float d47 = d45 * d67;
          float num = fmaf(n03, d47, n47 * d03);
          float den = d03 * d47;
          acc[a][cc] = fmaf(num, __builtin_amdgcn_rcpf(den), acc[a][cc]);
        }
      }
    }
    __syncthreads();
    if (c < 15) {
      *(float4*)(dpl + pos0) = pd0;
      *(float4*)(dpl + pos1) = pd1;
      *(float4*)(epl + pos0) = pe0;
      *(float4*)(epl + pos1) = pe1;
      __syncthreads();
    }
  }

  const float base = svbv[0];
#pragma unroll
  for (int a = 0; a < 4; ++a) {
    size_t orow = ((size_t)b * NT + t0 + 4 * ti + a) * NL + l0 + 4 * lj;
    float4 ov;
    ov.x = base - 2.f * acc[a][0];
    ov.y = base - 2.f * acc[a][1];
    ov.z = base - 2.f * acc[a][2];
    ov.w = base - 2.f * acc[a][3];
    *(float4*)(out + orow) = ov;
  }
}

// ------------------------- K4: sequential mask/softmax/argmax, in-place on d_out
__global__ __launch_bounds__(64) void k_seq(float* __restrict__ out) {
  const int b = blockIdx.x;
  const int lane = threadIdx.x;
  float* base = out + (size_t)b * NT * NL;
  float maskf[8];
#pragma unroll
  for (int k = 0; k < 8; ++k) maskf[k] = 0.f;
  float cur[8];
#pragma unroll
  for (int k = 0; k < 8; ++k) cur[k] = base[lane + 64 * k];

  for (int t = 0; t < NT; ++t) {
    float nxt[8] = {0.f, 0.f, 0.f, 0.f, 0.f, 0.f, 0.f, 0.f};
    if (t + 1 < NT) {
      const float* nr = base + (size_t)(t + 1) * NL;
#pragma unroll
      for (int k = 0; k < 8; ++k) nxt[k] = nr[lane + 64 * k];
    }
    float e[8];
    float psum = 0.f;
    float mval = -3.4e38f;
    int midx = 0x7fffffff;
#pragma unroll
    for (int k = 0; k < 8; ++k) {
      float v = cur[k] - maskf[k] * 1000000.0f;
      e[k] = __expf(v);
      psum += e[k];
      int idx = lane + 64 * k;
      if (v > mval || (v == mval && idx < midx)) { mval = v; midx = idx; }
    }
#pragma unroll
    for (int off = 32; off > 0; off >>= 1) {
      float ov = __shfl_xor(mval, off);
      int oi = __shfl_xor(midx, off);
      float ps = __shfl_xor(psum, off);
      psum += ps;
      if (ov > mval || (ov == mval && oi < midx)) { mval = ov; midx = oi; }
    }
    const float inv = 1.0f / psum;
    float* orow = base + (size_t)t * NL;
#pragma unroll
    for (int k = 0; k < 8; ++k) orow[lane + 64 * k] = e[k] * inv;
#pragma unroll
    for (int k = 0; k < 8; ++k)
      if (lane + 64 * k == midx) maskf[k] += 1.0f;
#pragma unroll
    for (int k = 0; k < 8; ++k) cur[k] = nxt[k];
  }
}

extern "C" void kernel_launch(void* const* d_in, const int* in_sizes, int n_in,
                              void* d_out, int out_size, void* d_ws, size_t ws_size,
                              hipStream_t stream) {
  const float* dec_outputs = (const float*)d_in[0];  // [B,T,H]
  const float* enc_outputs = (const float*)d_in[1];  // [B,L,H]
  const float* W1 = (const float*)d_in[3];
  const float* b1 = (const float*)d_in[4];
  const float* W2 = (const float*)d_in[5];
  const float* b2 = (const float*)d_in[6];
  const float* V  = (const float*)d_in[7];
  const float* bV = (const float*)d_in[8];
  float* out = (float*)d_out;  // [B,T,L] f32

  // ws layout: [svbv 256B][Ed 134.2MB][Ee 134.2MB][W^T fp16 4x512KB][A fp16 h+l 134.2MB?]
  const size_t nEd = (size_t)NB * NT * NU;           // 33.55M elems
  const size_t nW = (size_t)NH * NU;                 // 262144 elems
  float* svbv = (float*)d_ws;
  float* Ed = (float*)((char*)d_ws + 256);
  float* Ee = Ed + nEd;
  h16* W1hT = (h16*)(Ee + nEd);
  h16* W1lT = W1hT + nW;
  h16* W2hT = W1lT + nW;
  h16* W2lT = W2hT + nW;
  h16* Ah = W2lT + nW;                               // reused for enc then dec
  h16* Al = Ah + nEd;
  const size_t needed = 256 + 2 * nEd * 4 + 4 * nW * 2 + 2 * nEd * 2;
  const bool direct = (ws_size >= needed);

  hipLaunchKernelGGL(k_sumv, dim3(1), dim3(256), 0, stream, V, bV, svbv);
  hipLaunchKernelGGL(k_prep, dim3(NU / 64, NH / 64), dim3(256), 0, stream,
                     W1, W1hT, W1lT);
  hipLaunchKernelGGL(k_prep, dim3(NU / 64, NH / 64), dim3(256), 0, stream,
                     W2, W2hT, W2lT);
  if (direct) {
    const int n4 = (int)(nEd / 4);
    hipLaunchKernelGGL(k_prep_a, dim3(2048), dim3(256), 0, stream,
                       enc_outputs, Ah, Al, n4);
    hipLaunchKernelGGL(k_proj_mfma_d, dim3(NU / 128, (NB * NL) / 128), dim3(256), 0, stream,
                       Ah, Al, W2hT, W2lT, b2, Ee);
    hipLaunchKernelGGL(k_prep_a, dim3(2048), dim3(256), 0, stream,
                       dec_outputs, Ah, Al, n4);
    hipLaunchKernelGGL(k_proj_mfma_d, dim3(NU / 128, (NB * NT) / 128), dim3(256), 0, stream,
                       Ah, Al, W1hT, W1lT, b1, Ed);
  } else {
    hipLaunchKernelGGL(k_proj_mfma, dim3(NU / 128, (NB * NT) / 128), dim3(256), 0, stream,
                       dec_outputs, W1hT, W1lT, b1, Ed);
    hipLaunchKernelGGL(k_proj_mfma, dim3(NU / 128, (NB * NL) / 128), dim3(256), 0, stream,
                       enc_outputs, W2hT, W2lT, b2, Ee);
  }
  hipLaunchKernelGGL(k_score, dim3(NL / 64, NT / 64, NB), dim3(256), 0, stream,
                     Ed, Ee, V, svbv, out);
  hipLaunchKernelGGL(k_seq, dim3(NB), dim3(64), 0, stream, out);
}

// Round 17
// 2354.355 us; speedup vs baseline: 1.0848x; 1.0848x over previous
//
#include <hip/hip_runtime.h>
#include <cstdint>

#define NB 128
#define NT 512
#define NL 512
#define NH 512
#define NU 512

// 2*log2(e): tanh(x) = 1 - 2/(exp2(K2E*x)+1); exp2 hoisted into the GEMM epilogue.
static constexpr float K2E = 2.8853900817779268f;

typedef _Float16 h16;
typedef h16 half8 __attribute__((ext_vector_type(8)));
typedef h16 half4 __attribute__((ext_vector_type(4)));
typedef float f32x4 __attribute__((ext_vector_type(4)));

// ---------------------------------------------------------------- K0: sum(V)+bV
__global__ __launch_bounds__(256) void k_sumv(const float* __restrict__ V,
                                              const float* __restrict__ bV,
                                              float* __restrict__ svbv) {
  __shared__ float red[256];
  int tid = threadIdx.x;
  red[tid] = V[tid] + V[tid + 256];
  __syncthreads();
  for (int off = 128; off > 0; off >>= 1) {
    if (tid < off) red[tid] += red[tid + off];
    __syncthreads();
  }
  if (tid == 0) svbv[0] = red[0] + bV[0];
}

// ------------------- K_prep: W [k][n] f32 -> WhT, WlT [n][k] fp16 (split hi/lo)
__global__ __launch_bounds__(256) void k_prep(const float* __restrict__ W,
                                              h16* __restrict__ WhT,
                                              h16* __restrict__ WlT) {
  __shared__ float t[64][65];
  const int tid = threadIdx.x;
  const int k0 = blockIdx.y * 64;
  const int n0 = blockIdx.x * 64;
  const int r = tid >> 4, c4 = (tid & 15) * 4;
#pragma unroll
  for (int p = 0; p < 4; ++p) {
    int k = r + p * 16;
    float4 v = *(const float4*)(W + (size_t)(k0 + k) * NU + n0 + c4);
    t[c4 + 0][k] = v.x;
    t[c4 + 1][k] = v.y;
    t[c4 + 2][k] = v.z;
    t[c4 + 3][k] = v.w;
  }
  __syncthreads();
#pragma unroll
  for (int p = 0; p < 4; ++p) {
    int n = r + p * 16;
    half4 h, l;
    float vv[4] = {t[n][c4 + 0], t[n][c4 + 1], t[n][c4 + 2], t[n][c4 + 3]};
    h.x = (h16)vv[0]; l.x = (h16)(vv[0] - (float)h.x);
    h.y = (h16)vv[1]; l.y = (h16)(vv[1] - (float)h.y);
    h.z = (h16)vv[2]; l.z = (h16)(vv[2] - (float)h.z);
    h.w = (h16)vv[3]; l.w = (h16)(vv[3] - (float)h.w);
    *(half4*)(WhT + (size_t)(n0 + n) * NH + k0 + c4) = h;
    *(half4*)(WlT + (size_t)(n0 + n) * NH + k0 + c4) = l;
  }
}

// --------------------- K1/K2: out = exp2(K2E*(A@W + bias)) via fp16x3 MFMA
// R15 (measured best): A staged through LDS fp16 hi/lo (block-level cache,
// 20.5 KB); B-fragments direct from precomputed WhT/WlT (L2-resident).
// Bracketed: R12-style pipelining regressed, R16 de-staging regressed.
#define PSTR 40
__global__ __launch_bounds__(256) void k_proj_mfma(const float* __restrict__ A,
                                                   const h16* __restrict__ WhT,
                                                   const h16* __restrict__ WlT,
                                                   const float* __restrict__ bias,
                                                   float* __restrict__ out) {
  __shared__ __align__(16) h16 Ah[128 * PSTR];
  __shared__ __align__(16) h16 Al[128 * PSTR];
  const int tid = threadIdx.x;
  const int m0 = blockIdx.y * 128;
  const int n0 = blockIdx.x * 128;
  const int lane = tid & 63;
  const int wid = tid >> 6;
  const int wm = (wid >> 1) * 64;
  const int wn = (wid & 1) * 64;
  const int fr = lane & 15;
  const int fg = lane >> 4;
  const int ar = tid >> 1, ak = (tid & 1) * 16;

  f32x4 acc[4][4];
#pragma unroll
  for (int tm = 0; tm < 4; ++tm)
#pragma unroll
    for (int tn = 0; tn < 4; ++tn) acc[tm][tn] = (f32x4){0.f, 0.f, 0.f, 0.f};

#pragma unroll 1
  for (int kc = 0; kc < 16; ++kc) {
#pragma unroll
    for (int q = 0; q < 4; ++q) {
      float4 v = *(const float4*)(A + (size_t)(m0 + ar) * NH + kc * 32 + ak + 4 * q);
      half4 h, l;
      h.x = (h16)v.x; l.x = (h16)(v.x - (float)h.x);
      h.y = (h16)v.y; l.y = (h16)(v.y - (float)h.y);
      h.z = (h16)v.z; l.z = (h16)(v.z - (float)h.z);
      h.w = (h16)v.w; l.w = (h16)(v.w - (float)h.w);
      *(half4*)(Ah + ar * PSTR + ak + 4 * q) = h;
      *(half4*)(Al + ar * PSTR + ak + 4 * q) = l;
    }
    __syncthreads();
    half8 bh[4], bl[4];
#pragma unroll
    for (int tn = 0; tn < 4; ++tn) {
      size_t boff = (size_t)(n0 + wn + tn * 16 + fr) * NH + kc * 32 + 8 * fg;
      bh[tn] = *(const half8*)(WhT + boff);
      bl[tn] = *(const half8*)(WlT + boff);
    }
#pragma unroll
    for (int tm = 0; tm < 4; ++tm) {
      half8 ah = *(const half8*)(Ah + (wm + tm * 16 + fr) * PSTR + 8 * fg);
      half8 al = *(const half8*)(Al + (wm + tm * 16 + fr) * PSTR + 8 * fg);
#pragma unroll
      for (int tn = 0; tn < 4; ++tn) {
        acc[tm][tn] = __builtin_amdgcn_mfma_f32_16x16x32_f16(ah, bh[tn], acc[tm][tn], 0, 0, 0);
        acc[tm][tn] = __builtin_amdgcn_mfma_f32_16x16x32_f16(ah, bl[tn], acc[tm][tn], 0, 0, 0);
        acc[tm][tn] = __builtin_amdgcn_mfma_f32_16x16x32_f16(al, bh[tn], acc[tm][tn], 0, 0, 0);
      }
    }
    __syncthreads();
  }
#pragma unroll
  for (int tn = 0; tn < 4; ++tn) {
    const int gn = n0 + wn + tn * 16 + fr;
    const float bsv = bias[gn];
#pragma unroll
    for (int tm = 0; tm < 4; ++tm) {
#pragma unroll
      for (int rg = 0; rg < 4; ++rg) {
        int gm = m0 + wm + tm * 16 + 4 * fg + rg;
        out[(size_t)gm * NU + gn] =
            __builtin_amdgcn_exp2f(K2E * (acc[tm][tn][rg] + bsv));
      }
    }
  }
}

// ---------------------------------------------- K3: S[b,t,l] = base - 2*sum_u V*rc
// R10/R13/R14/R15 version (measured best ~1.52-1.65 ms, VGPR 68, VALUBusy 91%).
__global__ __launch_bounds__(256) void k_score(const float* __restrict__ Ed,
                                               const float* __restrict__ Ee,
                                               const float* __restrict__ Vv,
                                               const float* __restrict__ svbv,
                                               float* __restrict__ out) {
  __shared__ float dpl[64 * 32];
  __shared__ float epl[64 * 32];
  const int tid = threadIdx.x;
  const int b = blockIdx.z;
  const int t0 = blockIdx.y * 64;
  const int l0 = blockIdx.x * 64;
  const int ti = tid & 15;
  const int lj = tid >> 4;
  const int tt = tid & 63;
  const int g0 = (tid >> 6) * 2;
  const float* Edb = Ed + ((size_t)b * NT + t0) * NU;
  const float* Eeb = Ee + ((size_t)b * NL + l0) * NU;
  const int sw = (tt ^ (tt >> 3)) & 7;
  const int pos0 = tt * 32 + 4 * ((g0 + 0) ^ sw);
  const int pos1 = tt * 32 + 4 * ((g0 + 1) ^ sw);
  const size_t srow = (size_t)tt * NU;

  float acc[4][4];
#pragma unroll
  for (int a = 0; a < 4; ++a)
#pragma unroll
    for (int c = 0; c < 4; ++c) acc[a][c] = 0.f;

  {
    float4 d0 = *(const float4*)(Edb + srow + 4 * g0);
    float4 d1 = *(const float4*)(Edb + srow + 4 * g0 + 4);
    float4 e0 = *(const float4*)(Eeb + srow + 4 * g0);
    float4 e1 = *(const float4*)(Eeb + srow + 4 * g0 + 4);
    *(float4*)(dpl + pos0) = d0;
    *(float4*)(dpl + pos1) = d1;
    *(float4*)(epl + pos0) = e0;
    *(float4*)(epl + pos1) = e1;
  }
  __syncthreads();

#pragma unroll 1
  for (int c = 0; c < 16; ++c) {
    float4 pd0, pd1, pe0, pe1;
    if (c < 15) {
      const int uc = (c + 1) * 32;
      pd0 = *(const float4*)(Edb + srow + uc + 4 * g0);
      pd1 = *(const float4*)(Edb + srow + uc + 4 * g0 + 4);
      pe0 = *(const float4*)(Eeb + srow + uc + 4 * g0);
      pe1 = *(const float4*)(Eeb + srow + uc + 4 * g0 + 4);
    }
#pragma unroll 1
    for (int g8 = 0; g8 < 4; ++g8) {
      const float* vb = Vv + c * 32 + g8 * 8;
      const float v0 = vb[0], v1 = vb[1], v2 = vb[2], v3 = vb[3];
      const float v4_ = vb[4], v5 = vb[5], v6 = vb[6], v7 = vb[7];
      float4 bLo[4], bHi[4];
#pragma unroll
      for (int r = 0; r < 4; ++r) {
        int rowb = 4 * lj + r;
        int swb = (rowb ^ (rowb >> 3)) & 7;
        bLo[r] = *(const float4*)(epl + rowb * 32 + 4 * ((2 * g8 + 0) ^ swb));
        bHi[r] = *(const float4*)(epl + rowb * 32 + 4 * ((2 * g8 + 1) ^ swb));
      }
#pragma unroll
      for (int a = 0; a < 4; ++a) {
        int rowa = 4 * ti + a;
        int swa = (rowa ^ (rowa >> 3)) & 7;
        float4 aLo = *(const float4*)(dpl + rowa * 32 + 4 * ((2 * g8 + 0) ^ swa));
        float4 aHi = *(const float4*)(dpl + rowa * 32 + 4 * ((2 * g8 + 1) ^ swa));
#pragma unroll
        for (int cc = 0; cc < 4; ++cc) {
          const float* bp = (const float*)&bLo[cc];
          const float* bh = (const float*)&bHi[cc];
          float d0 = fmaf(aLo.x, bp[0], 1.0f);
          float d1 = fmaf(aLo.y, bp[1], 1.0f);
          float d2 = fmaf(aLo.z, bp[2], 1.0f);
          float d3 = fmaf(aLo.w, bp[3], 1.0f);
          float d4 = fmaf(aHi.x, bh[0], 1.0f);
          float d5 = fmaf(aHi.y, bh[1], 1.0f);
          float d6 = fmaf(aHi.z, bh[2], 1.0f);
          float d7 = fmaf(aHi.w, bh[3], 1.0f);
          float d01 = d0 * d1, d23 = d2 * d3, d45 = d4 * d5, d67 = d6 * d7;
          float n01 = fmaf(v0, d1, v1 * d0);
          float n23 = fmaf(v2, d3, v3 * d2);
          float n45 = fmaf(v4_, d5, v5 * d4);
          float n67 = fmaf(v6, d7, v7 * d6);
          float n03 = fmaf(n01, d23, n23 * d01);
          float d03 = d01 * d23;
          float n47 = fmaf(n45, d67, n67 * d45);
          float d47 = d45 * d67;
          float num = fmaf(n03, d47, n47 * d03);
          float den = d03 * d47;
          acc[a][cc] = fmaf(num, __builtin_amdgcn_rcpf(den), acc[a][cc]);
        }
      }
    }
    __syncthreads();
    if (c < 15) {
      *(float4*)(dpl + pos0) = pd0;
      *(float4*)(dpl + pos1) = pd1;
      *(float4*)(epl + pos0) = pe0;
      *(float4*)(epl + pos1) = pe1;
      __syncthreads();
    }
  }

  const float base = svbv[0];
#pragma unroll
  for (int a = 0; a < 4; ++a) {
    size_t orow = ((size_t)b * NT + t0 + 4 * ti + a) * NL + l0 + 4 * lj;
    float4 ov;
    ov.x = base - 2.f * acc[a][0];
    ov.y = base - 2.f * acc[a][1];
    ov.z = base - 2.f * acc[a][2];
    ov.w = base - 2.f * acc[a][3];
    *(float4*)(out + orow) = ov;
  }
}

// ------------------------- K4: sequential mask/softmax/argmax, in-place on d_out
__global__ __launch_bounds__(64) void k_seq(float* __restrict__ out) {
  const int b = blockIdx.x;
  const int lane = threadIdx.x;
  float* base = out + (size_t)b * NT * NL;
  float maskf[8];
#pragma unroll
  for (int k = 0; k < 8; ++k) maskf[k] = 0.f;
  float cur[8];
#pragma unroll
  for (int k = 0; k < 8; ++k) cur[k] = base[lane + 64 * k];

  for (int t = 0; t < NT; ++t) {
    float nxt[8] = {0.f, 0.f, 0.f, 0.f, 0.f, 0.f, 0.f, 0.f};
    if (t + 1 < NT) {
      const float* nr = base + (size_t)(t + 1) * NL;
#pragma unroll
      for (int k = 0; k < 8; ++k) nxt[k] = nr[lane + 64 * k];
    }
    float e[8];
    float psum = 0.f;
    float mval = -3.4e38f;
    int midx = 0x7fffffff;
#pragma unroll
    for (int k = 0; k < 8; ++k) {
      float v = cur[k] - maskf[k] * 1000000.0f;
      e[k] = __expf(v);
      psum += e[k];
      int idx = lane + 64 * k;
      if (v > mval || (v == mval && idx < midx)) { mval = v; midx = idx; }
    }
#pragma unroll
    for (int off = 32; off > 0; off >>= 1) {
      float ov = __shfl_xor(mval, off);
      int oi = __shfl_xor(midx, off);
      float ps = __shfl_xor(psum, off);
      psum += ps;
      if (ov > mval || (ov == mval && oi < midx)) { mval = ov; midx = oi; }
    }
    const float inv = 1.0f / psum;
    float* orow = base + (size_t)t * NL;
#pragma unroll
    for (int k = 0; k < 8; ++k) orow[lane + 64 * k] = e[k] * inv;
#pragma unroll
    for (int k = 0; k < 8; ++k)
      if (lane + 64 * k == midx) maskf[k] += 1.0f;
#pragma unroll
    for (int k = 0; k < 8; ++k) cur[k] = nxt[k];
  }
}

extern "C" void kernel_launch(void* const* d_in, const int* in_sizes, int n_in,
                              void* d_out, int out_size, void* d_ws, size_t ws_size,
                              hipStream_t stream) {
  const float* dec_outputs = (const float*)d_in[0];  // [B,T,H]
  const float* enc_outputs = (const float*)d_in[1];  // [B,L,H]
  const float* W1 = (const float*)d_in[3];
  const float* b1 = (const float*)d_in[4];
  const float* W2 = (const float*)d_in[5];
  const float* b2 = (const float*)d_in[6];
  const float* V  = (const float*)d_in[7];
  const float* bV = (const float*)d_in[8];
  float* out = (float*)d_out;  // [B,T,L] f32

  // workspace: [svbv 256B][Ed 134.2MB][Ee 134.2MB][W1hT|W1lT|W2hT|W2lT 4x512KB]
  float* svbv = (float*)d_ws;
  float* Ed = (float*)((char*)d_ws + 256);
  float* Ee = Ed + (size_t)NB * NT * NU;
  h16* W1hT = (h16*)(Ee + (size_t)NB * NL * NU);
  h16* W1lT = W1hT + (size_t)NH * NU;
  h16* W2hT = W1lT + (size_t)NH * NU;
  h16* W2lT = W2hT + (size_t)NH * NU;

  hipLaunchKernelGGL(k_sumv, dim3(1), dim3(256), 0, stream, V, bV, svbv);
  hipLaunchKernelGGL(k_prep, dim3(NU / 64, NH / 64), dim3(256), 0, stream,
                     W1, W1hT, W1lT);
  hipLaunchKernelGGL(k_prep, dim3(NU / 64, NH / 64), dim3(256), 0, stream,
                     W2, W2hT, W2lT);
  hipLaunchKernelGGL(k_proj_mfma, dim3(NU / 128, (NB * NT) / 128), dim3(256), 0, stream,
                     dec_outputs, W1hT, W1lT, b1, Ed);
  hipLaunchKernelGGL(k_proj_mfma, dim3(NU / 128, (NB * NL) / 128), dim3(256), 0, stream,
                     enc_outputs, W2hT, W2lT, b2, Ee);
  hipLaunchKernelGGL(k_score, dim3(NL / 64, NT / 64, NB), dim3(256), 0, stream,
                     Ed, Ee, V, svbv, out);
  hipLaunchKernelGGL(k_seq, dim3(NB), dim3(64), 0, stream, out);
}